// Round 1
// baseline (406.790 us; speedup 1.0000x reference)
//
#include <hip/hip_runtime.h>
#include <hip/hip_bf16.h>

// GraphVertEdgeNet on MI355X. B=64, N=64, VF=32, EF=16, DV=DE=128, LN=4.
// e stored bf16 in ws (64MB), TRANSPOSED layout e_t[b][j][i][c] AND
// XOR-swizzled within each (b,j0) 32KB tile: byte ^= ((i&7)<<4). This makes
// all HBM<->LDS staging a pure identity copy (global_load_lds width-16,
// fully coalesced) while LDS fragment reads stay ~2-way bank-conflict-free
// without padding. Small fp32 matmul kernels widened to 1024 blocks (16
// waves/CU) for L2-latency hiding; k_g3 widened to 1024 threads.

typedef __bf16 bf16_t;
typedef __bf16 bf16x8 __attribute__((ext_vector_type(8)));
typedef __bf16 bf16x4 __attribute__((ext_vector_type(4)));
typedef float f32x4 __attribute__((ext_vector_type(4)));

// Barrier that does NOT drain vmcnt: safe when cross-wave deps are LDS-only.
__device__ __forceinline__ void bar_lgkm() {
  asm volatile("s_waitcnt lgkmcnt(0)\n\ts_barrier" ::: "memory");
}
// Barrier that drains vmcnt (for global_load_lds staging) but not lgkm.
__device__ __forceinline__ void bar_vm() {
  asm volatile("s_waitcnt vmcnt(0)\n\ts_barrier" ::: "memory");
}

// XOR swizzle of a byte offset within one 32KB e-tile (2 j-cols x 64 i x 128c).
// lin = (jc<<14) | (i<<8) | (c<<1); row bits 8..10 XOR'd into bank bits 4..6.
__device__ __forceinline__ int swz(int lin) { return lin ^ (((lin >> 8) & 7) << 4); }

__device__ __forceinline__ void gload_lds16(const void* g, void* l) {
  __builtin_amdgcn_global_load_lds(
      (const __attribute__((address_space(1))) void*)g,
      (__attribute__((address_space(3))) void*)l, 16, 0, 0);
}

// ---------------- prep: input BN (v0), Wt transpose, zero stats ----------------
__global__ __launch_bounds__(256) void k_prep(const float* __restrict__ vin,
    const float* __restrict__ g, const float* __restrict__ bt,
    const float* __restrict__ eW, float* __restrict__ v0,
    bf16_t* __restrict__ Wt, float* __restrict__ stats) {
  const int blk = blockIdx.x, tid = threadIdx.x;
  if (blk < 8) {  // BatchNorm1d(N*VF) over batch, ch = 0..2047
    int ch = blk * 256 + tid;
    float s = 0.f, s2 = 0.f;
    for (int b = 0; b < 64; ++b) { float x = vin[b * 2048 + ch]; s += x; s2 += x * x; }
    float mu = s * (1.f / 64.f);
    float var = s2 * (1.f / 64.f) - mu * mu;  // biased var
    float sc = rsqrtf(var + 1e-5f) * g[ch];
    float bb = bt[ch];
    for (int b = 0; b < 64; ++b) {
      float x = vin[b * 2048 + ch];
      v0[b * 2048 + ch] = (x - mu) * sc + bb;
    }
  } else if (blk < 264) {  // Wt[l][n][k] = eW[l][k][n] as bf16
    int idx = (blk - 8) * 256 + tid;  // 4*128*128 = 65536
    int l = idx >> 14, r = idx & 16383, n = r >> 7, k = r & 127;
    Wt[idx] = (bf16_t)eW[(l << 14) + (k << 7) + n];
  } else {  // zero stats (512 f32)
    for (int i = tid; i < 512; i += 256) stats[i] = 0.f;
  }
}

// ------------- ev = v_in @ W + bias : [4096,K]@[K,128]. 256 thr, 4 rows/blk -------------
template <int K>
__global__ __launch_bounds__(256) void k_ev(const float* __restrict__ v_in,
    const float* __restrict__ W, const float* __restrict__ bias,
    float* __restrict__ out) {
  __shared__ float rows_s[4][K];
  const int r0 = blockIdx.x * 4;
  const int tid = threadIdx.x;
  const int c = tid & 127, h = tid >> 7;  // h: rows h*2 .. h*2+1
  for (int idx = tid; idx < 4 * K; idx += 256) {
    int rr = idx / K, kk = idx % K;
    rows_s[rr][kk] = v_in[(r0 + rr) * K + kk];
  }
  __syncthreads();
  float acc[2];
  const float bv = bias[c];
  acc[0] = bv; acc[1] = bv;
  for (int k4 = 0; k4 < K; k4 += 4) {
    float w0 = W[(k4 + 0) * 128 + c], w1 = W[(k4 + 1) * 128 + c];
    float w2 = W[(k4 + 2) * 128 + c], w3 = W[(k4 + 3) * 128 + c];
#pragma unroll
    for (int r = 0; r < 2; ++r) {
      float4 x = *(const float4*)&rows_s[h * 2 + r][k4];
      acc[r] += x.x * w0 + x.y * w1 + x.z * w2 + x.w * w3;
    }
  }
#pragma unroll
  for (int r = 0; r < 2; ++r) out[(r0 + h * 2 + r) * 128 + c] = acc[r];
}

// ------------- fused BN(prev) + ev matmul (in-place v normalize). 4 rows/blk -------------
__global__ __launch_bounds__(256) void k_evbn(float* __restrict__ v,
    const float* __restrict__ stats, const float* __restrict__ g,
    const float* __restrict__ bt, const float* __restrict__ W,
    const float* __restrict__ bias, float* __restrict__ out) {
  __shared__ float rows_s[4][128];
  const int r0 = blockIdx.x * 4;
  const int tid = threadIdx.x;
  const int c = tid & 127, h = tid >> 7;
#pragma unroll
  for (int u = 0; u < 2; ++u) {
    int idx = u * 256 + tid;
    int rr = idx >> 7, k = idx & 127;
    int n = (r0 + rr) & 63;
    float mu = stats[n] * (1.f / 8192.f);
    float var = stats[64 + n] * (1.f / 8192.f) - mu * mu;
    float sc = rsqrtf(var + 128.f) * g[n];
    float x = (v[(r0 + rr) * 128 + k] - mu) * sc + bt[n];
    rows_s[rr][k] = x;
    v[(r0 + rr) * 128 + k] = x;  // normalized v for residual/concat
  }
  __syncthreads();
  float acc[2];
  const float bv = bias[c];
  acc[0] = bv; acc[1] = bv;
  for (int k4 = 0; k4 < 128; k4 += 4) {
    float w0 = W[(k4 + 0) * 128 + c], w1 = W[(k4 + 1) * 128 + c];
    float w2 = W[(k4 + 2) * 128 + c], w3 = W[(k4 + 3) * 128 + c];
#pragma unroll
    for (int r = 0; r < 2; ++r) {
      float4 x = *(const float4*)&rows_s[h * 2 + r][k4];
      acc[r] += x.x * w0 + x.y * w1 + x.z * w2 + x.w * w3;
    }
  }
#pragma unroll
  for (int r = 0; r < 2; ++r) out[(r0 + h * 2 + r) * 128 + c] = acc[r];
}

// ------------- g1 edge pass (MFMA, K 16->32 zero-pad, 2 j/block) -------------
// Writes e_t[b][j][i][c] in the swizzled layout: copy-out is identity bytes.
__global__ __launch_bounds__(256) void k_edge_g1(const float* __restrict__ e0,
    const float* __restrict__ eW, const float* __restrict__ eb,
    const float* __restrict__ ev, bf16_t* __restrict__ e_ws,
    float* __restrict__ pve) {
  __shared__ bf16_t A0s[2][64][40];
  __shared__ __align__(16) bf16_t Os[2 * 64 * 128];  // swizzled tile
  const int b = blockIdx.x >> 5, j0 = (blockIdx.x & 31) * 2;
  const int tid = threadIdx.x;
  const int lane = tid & 63, w = tid >> 6;
  const int quad = lane >> 4, l16 = lane & 15;
#pragma unroll
  for (int t = 0; t < 2; ++t) {
    int idx = tid + t * 256;
    int row = idx >> 3, off = (idx & 7) * 4;
    int jc = off >> 4, k = off & 15;
    f32x4 x = *(const f32x4*)&e0[((b * 64 + row) * 64 + j0) * 16 + off];
    bf16x4 y;
#pragma unroll
    for (int r = 0; r < 4; ++r) y[r] = (bf16_t)x[r];
    *(bf16x4*)&A0s[jc][row][k] = y;
    bf16x4 z = {(bf16_t)0.f, (bf16_t)0.f, (bf16_t)0.f, (bf16_t)0.f};
    *(bf16x4*)&A0s[jc][row][16 + k] = z;
  }
  const int c0[2] = {w * 32 + quad * 4, w * 32 + 16 + quad * 4};
  bf16x8 wf[2];
#pragma unroll
  for (int nt = 0; nt < 2; ++nt) {
    const int c = w * 32 + nt * 16 + l16;
#pragma unroll
    for (int jj = 0; jj < 8; ++jj)
      wf[nt][jj] = (quad < 2) ? (bf16_t)eW[(quad * 8 + jj) * 128 + c] : (bf16_t)0.f;
  }
  f32x4 acc[2][4][2];
  {
    f32x4 ebv[2], evj[2][2], evi[4][2];
#pragma unroll
    for (int nt = 0; nt < 2; ++nt) {
      ebv[nt] = *(const f32x4*)&eb[c0[nt]];
#pragma unroll
      for (int jc = 0; jc < 2; ++jc)
        evj[jc][nt] = *(const f32x4*)&ev[(b * 64 + j0 + jc) * 128 + c0[nt]];
#pragma unroll
      for (int mt = 0; mt < 4; ++mt)
        evi[mt][nt] = *(const f32x4*)&ev[(b * 64 + mt * 16 + l16) * 128 + c0[nt]];
    }
#pragma unroll
    for (int jc = 0; jc < 2; ++jc)
#pragma unroll
      for (int mt = 0; mt < 4; ++mt)
#pragma unroll
        for (int nt = 0; nt < 2; ++nt)
          acc[jc][mt][nt] = ebv[nt] + evj[jc][nt] + evi[mt][nt];
  }
  __syncthreads();
#pragma unroll
  for (int jc = 0; jc < 2; ++jc) {
#pragma unroll
    for (int mt = 0; mt < 4; ++mt) {
      bf16x8 ef = *(const bf16x8*)&A0s[jc][mt * 16 + l16][quad * 8];
#pragma unroll
      for (int nt = 0; nt < 2; ++nt)
        acc[jc][mt][nt] = __builtin_amdgcn_mfma_f32_16x16x32_bf16(wf[nt], ef, acc[jc][mt][nt], 0, 0, 0);
    }
  }
#pragma unroll
  for (int jc = 0; jc < 2; ++jc) {
#pragma unroll
    for (int nt = 0; nt < 2; ++nt) {
      f32x4 ps = {0.f, 0.f, 0.f, 0.f};
#pragma unroll
      for (int mt = 0; mt < 4; ++mt) {
        const int i = mt * 16 + l16;
        bf16x4 outv;
#pragma unroll
        for (int r = 0; r < 4; ++r) {
          float vv = fmaxf(acc[jc][mt][nt][r], 0.f);
          ps[r] += vv;
          outv[r] = (bf16_t)vv;
        }
        *(bf16x4*)((char*)Os + swz(((jc * 64 + i) << 8) | (c0[nt] << 1))) = outv;
      }
#pragma unroll
      for (int m = 1; m <= 8; m <<= 1) {
#pragma unroll
        for (int r = 0; r < 4; ++r) ps[r] += __shfl_xor(ps[r], m);
      }
      if (l16 == 0) *(f32x4*)&pve[(b * 64 + j0 + jc) * 128 + c0[nt]] = ps;
    }
  }
  __syncthreads();
  {  // identity copy-out: HBM layout == swizzled LDS layout
    bf16_t* ebase = &e_ws[((size_t)(b * 64 + j0) * 64) * 128];
#pragma unroll
    for (int t = 0; t < 8; ++t) {
      int off = (t * 256 + tid) * 16;
      *(int4*)((char*)ebase + off) = *(const int4*)((const char*)Os + off);
    }
  }
}

// ------------- fused g1-v + layer0-ev. 256 thr, 4 rows/blk -------------
__global__ __launch_bounds__(256) void k_vg1_ev(const float* __restrict__ pve,
    const float* __restrict__ v0, const float* __restrict__ vW,
    const float* __restrict__ vb, const float* __restrict__ evW,
    const float* __restrict__ evb, float* __restrict__ v, float* __restrict__ ev) {
  __shared__ float in_s[4][160];
  __shared__ float vr[4][128];
  const int r0 = blockIdx.x * 4;
  const int tid = threadIdx.x;
  const int c = tid & 127, h = tid >> 7;
#pragma unroll
  for (int u = 0; u < 2; ++u) {
    int idx = u * 256 + tid;
    int rr = idx >> 7, k = idx & 127;
    in_s[rr][k] = pve[(r0 + rr) * 128 + k];
  }
  if (tid < 128) {
    int rr = tid >> 5, k = tid & 31;
    in_s[rr][128 + k] = v0[(r0 + rr) * 32 + k];
  }
  __syncthreads();
  float acc[2];
  const float bv = vb[c];
  acc[0] = bv; acc[1] = bv;
  for (int k4 = 0; k4 < 160; k4 += 4) {
    float w0 = vW[(k4 + 0) * 128 + c], w1 = vW[(k4 + 1) * 128 + c];
    float w2 = vW[(k4 + 2) * 128 + c], w3 = vW[(k4 + 3) * 128 + c];
#pragma unroll
    for (int r = 0; r < 2; ++r) {
      float4 x = *(const float4*)&in_s[h * 2 + r][k4];
      acc[r] += x.x * w0 + x.y * w1 + x.z * w2 + x.w * w3;
    }
  }
#pragma unroll
  for (int r = 0; r < 2; ++r) {
    float val = fmaxf(acc[r], 0.f);
    vr[h * 2 + r][c] = val;
    v[(r0 + h * 2 + r) * 128 + c] = val;
  }
  __syncthreads();
  float acc2[2];
  const float bv2 = evb[c];
  acc2[0] = bv2; acc2[1] = bv2;
  for (int k4 = 0; k4 < 128; k4 += 4) {
    float w0 = evW[(k4 + 0) * 128 + c], w1 = evW[(k4 + 1) * 128 + c];
    float w2 = evW[(k4 + 2) * 128 + c], w3 = evW[(k4 + 3) * 128 + c];
#pragma unroll
    for (int r = 0; r < 2; ++r) {
      float4 x = *(const float4*)&vr[h * 2 + r][k4];
      acc2[r] += x.x * w0 + x.y * w1 + x.z * w2 + x.w * w3;
    }
  }
#pragma unroll
  for (int r = 0; r < 2; ++r) ev[(r0 + h * 2 + r) * 128 + c] = acc2[r];
}

// ------------- inner edge pass: global_load_lds identity stage of swizzled tile ----------
// e += relu(e@W + eb + ev_i + ev_j); pve = pre-residual col sums.
// LAST: instead of e write-back, computes edot[b][j][i] = dot(e_new[b,i,j,:], eW3).
template <bool LAST>
__global__ __launch_bounds__(256) void k_edge_inner(bf16_t* __restrict__ e_ws,
    const bf16_t* __restrict__ Wt, const float* __restrict__ eb,
    const float* __restrict__ ev, float* __restrict__ pve,
    const float* __restrict__ eW3, float* __restrict__ edt) {
  __shared__ __align__(16) bf16_t As[2 * 64 * 128];  // swizzled tile, 32KB
  __shared__ float W3s[128];
  const int b = blockIdx.x >> 5, j0 = (blockIdx.x & 31) * 2;
  const int tid = threadIdx.x;
  const int lane = tid & 63, w = tid >> 6;
  const int quad = lane >> 4, l16 = lane & 15;
  bf16_t* ebase = &e_ws[((size_t)(b * 64 + j0) * 64) * 128];
  // async global->LDS stage: identity bytes (layout pre-swizzled in HBM)
  {
    const char* gsrc = (const char*)ebase;
    char* ldst = (char*)As;
#pragma unroll
    for (int t = 0; t < 8; ++t)
      gload_lds16(gsrc + (t * 256 + tid) * 16, ldst + (t * 256 + w * 64) * 16);
  }
  if (LAST) {
    if (tid < 128) W3s[tid] = eW3[tid];
  }
  // W A-frags in registers (L2-hot): A[m=c][k]
  bf16x8 wf[2][4];
#pragma unroll
  for (int nt = 0; nt < 2; ++nt)
#pragma unroll
    for (int ks = 0; ks < 4; ++ks)
      wf[nt][ks] = *(const bf16x8*)&Wt[(w * 32 + nt * 16 + l16) * 128 + ks * 32 + quad * 8];
  const int c0[2] = {w * 32 + quad * 4, w * 32 + 16 + quad * 4};
  // acc init = eb + ev_j + ev_i (overlapped with the LDS staging)
  f32x4 acc[2][4][2];
  {
    f32x4 ebv[2], evj[2][2], evi[4][2];
#pragma unroll
    for (int nt = 0; nt < 2; ++nt) {
      ebv[nt] = *(const f32x4*)&eb[c0[nt]];
#pragma unroll
      for (int jc = 0; jc < 2; ++jc)
        evj[jc][nt] = *(const f32x4*)&ev[(b * 64 + j0 + jc) * 128 + c0[nt]];
#pragma unroll
      for (int mt = 0; mt < 4; ++mt)
        evi[mt][nt] = *(const f32x4*)&ev[(b * 64 + mt * 16 + l16) * 128 + c0[nt]];
    }
#pragma unroll
    for (int jc = 0; jc < 2; ++jc)
#pragma unroll
      for (int mt = 0; mt < 4; ++mt)
#pragma unroll
        for (int nt = 0; nt < 2; ++nt)
          acc[jc][mt][nt] = ebv[nt] + evj[jc][nt] + evi[mt][nt];
  }
  bar_vm();  // staging complete in LDS for all waves
  // MFMA: D[c][i] = sum_k Wt[c][k] * e[i][k]  (64 MFMA per block)
#pragma unroll
  for (int ks = 0; ks < 4; ++ks) {
    bf16x8 ef[2][4];
#pragma unroll
    for (int jc = 0; jc < 2; ++jc)
#pragma unroll
      for (int mt = 0; mt < 4; ++mt)
        ef[jc][mt] = *(const bf16x8*)((const char*)As +
            swz(((jc * 64 + mt * 16 + l16) << 8) | ((ks * 32 + quad * 8) << 1)));
#pragma unroll
    for (int jc = 0; jc < 2; ++jc)
#pragma unroll
      for (int mt = 0; mt < 4; ++mt)
#pragma unroll
        for (int nt = 0; nt < 2; ++nt)
          acc[jc][mt][nt] = __builtin_amdgcn_mfma_f32_16x16x32_bf16(wf[nt][ks], ef[jc][mt], acc[jc][mt][nt], 0, 0, 0);
  }
  bar_lgkm();  // all MFMA frag reads of As done (LDS-only dep)
  // epilogue: relu, pve, residual from LDS, packed b64 writes to own cells
#pragma unroll
  for (int jc = 0; jc < 2; ++jc) {
#pragma unroll
    for (int nt = 0; nt < 2; ++nt) {
      f32x4 ps = {0.f, 0.f, 0.f, 0.f};
#pragma unroll
      for (int mt = 0; mt < 4; ++mt) {
        const int i = mt * 16 + l16;
        char* cell = (char*)As + swz(((jc * 64 + i) << 8) | (c0[nt] << 1));
        bf16x4 eo = *(const bf16x4*)cell;
        bf16x4 outv;
#pragma unroll
        for (int r = 0; r < 4; ++r) {
          float vv = fmaxf(acc[jc][mt][nt][r], 0.f);
          ps[r] += vv;                            // pve is pre-residual
          outv[r] = (bf16_t)(vv + (float)eo[r]);  // residual
        }
        *(bf16x4*)cell = outv;
      }
#pragma unroll
      for (int m = 1; m <= 8; m <<= 1) {  // reduce over i (l16 lanes)
#pragma unroll
        for (int r = 0; r < 4; ++r) ps[r] += __shfl_xor(ps[r], m);
      }
      if (l16 == 0) *(f32x4*)&pve[(b * 64 + j0 + jc) * 128 + c0[nt]] = ps;
    }
  }
  bar_lgkm();  // As fully updated (LDS-only dep)
  if (!LAST) {
    // identity write-back: preserves the swizzled HBM layout
#pragma unroll
    for (int t = 0; t < 8; ++t) {
      int off = (t * 256 + tid) * 16;
      *(int4*)((char*)ebase + off) = *(const int4*)((const char*)As + off);
    }
  } else {
    // edot[b][j][i] = dot(e_new[b,i,j,:], W3)
    const int i = tid >> 2, q = tid & 3;
#pragma unroll
    for (int jc = 0; jc < 2; ++jc) {
      float d = 0.f;
#pragma unroll
      for (int t = 0; t < 4; ++t) {
        bf16x8 x = *(const bf16x8*)((const char*)As +
            swz(((jc * 64 + i) << 8) | ((q * 32 + t * 8) << 1)));
#pragma unroll
        for (int u = 0; u < 8; ++u) d += (float)x[u] * W3s[q * 32 + t * 8 + u];
      }
      d += __shfl_xor(d, 1);
      d += __shfl_xor(d, 2);
      if (q == 0) edt[(b * 64 + j0 + jc) * 64 + i] = d;
    }
  }
}

// ------------- inner v pass: v = relu(concat(pve,v)@[256,128]+vb) + v; BN stats. 4 rows/blk ---
__global__ __launch_bounds__(256) void k_v_inner(const float* __restrict__ pve,
    float* __restrict__ v, const float* __restrict__ vW,
    const float* __restrict__ vb, float* __restrict__ stats) {
  __shared__ float in_s[4][256];
  __shared__ float outs[4][132];  // +4 pad
  __shared__ float part[8][2];
  const int r0 = blockIdx.x * 4;
  const int tid = threadIdx.x;
  const int c = tid & 127, h = tid >> 7;
#pragma unroll
  for (int u = 0; u < 2; ++u) {
    int idx = u * 256 + tid;
    int rr = idx >> 7, k = idx & 127;
    in_s[rr][k] = pve[(r0 + rr) * 128 + k];
    in_s[rr][128 + k] = v[(r0 + rr) * 128 + k];
  }
  __syncthreads();
  float acc[2];
  const float bv = vb[c];
  acc[0] = bv; acc[1] = bv;
  for (int k4 = 0; k4 < 256; k4 += 4) {
    float w0 = vW[(k4 + 0) * 128 + c], w1 = vW[(k4 + 1) * 128 + c];
    float w2 = vW[(k4 + 2) * 128 + c], w3 = vW[(k4 + 3) * 128 + c];
#pragma unroll
    for (int r = 0; r < 2; ++r) {
      float4 x = *(const float4*)&in_s[h * 2 + r][k4];
      acc[r] += x.x * w0 + x.y * w1 + x.z * w2 + x.w * w3;
    }
  }
#pragma unroll
  for (int r = 0; r < 2; ++r) {
    float val = fmaxf(acc[r], 0.f) + in_s[h * 2 + r][128 + c];  // relu + residual
    outs[h * 2 + r][c] = val;
    v[(r0 + h * 2 + r) * 128 + c] = val;
  }
  __syncthreads();
  if (tid < 8) {  // parallel BN-stat partial reduction
    int rr = tid >> 1, half = tid & 1;
    float s = 0.f, s2 = 0.f;
    for (int k = 0; k < 64; ++k) {
      float x = outs[rr][half * 64 + k];
      s += x; s2 += x * x;
    }
    part[tid][0] = s;
    part[tid][1] = s2;
  }
  __syncthreads();
  if (tid < 4) {
    int n = (r0 + tid) & 63;
    atomicAdd(&stats[n], part[tid * 2][0] + part[tid * 2 + 1][0]);
    atomicAdd(&stats[64 + n], part[tid * 2][1] + part[tid * 2 + 1][1]);
  }
}

// ------------- g3 final: per-b block, 1024 threads. BN(v), ev3, out_e = edot+eb3+ev3_i+ev3_j,
// pve3 in LDS, out_v. One kernel, 64 blocks. -------------
__global__ __launch_bounds__(1024) void k_g3(const float* __restrict__ vv,
    const float* __restrict__ stats3, const float* __restrict__ g,
    const float* __restrict__ bt, const float* __restrict__ evW3,
    const float* __restrict__ evb3, const float* __restrict__ eb3,
    const float* __restrict__ edt, const float* __restrict__ vW3,
    const float* __restrict__ vb3, float* __restrict__ out_v,
    float* __restrict__ out_e) {
  __shared__ float vbn[64][132];   // +4 pad
  __shared__ float edts[64][68];   // edt[b][j][i], +4 pad
  __shared__ float scs[64], shs[64];
  __shared__ float W3e[128];
  __shared__ float vWs[132];
  __shared__ float ev3s[64];
  __shared__ float pj[16][64];
  const int b = blockIdx.x, tid = threadIdx.x;
  if (tid < 64) {
    float mu = stats3[tid] * (1.f / 8192.f);
    float var = stats3[64 + tid] * (1.f / 8192.f) - mu * mu;
    float sc = rsqrtf(var + 128.f) * g[tid];
    scs[tid] = sc;
    shs[tid] = bt[tid] - mu * sc;
  }
  if (tid < 128) W3e[tid] = evW3[tid];
  if (tid < 129) vWs[tid] = vW3[tid];
  __syncthreads();
#pragma unroll
  for (int t = 0; t < 2; ++t) {  // stage BN(v[b])
    int idx = t * 4096 + tid * 4;
    int row = idx >> 7, cc = idx & 127;
    f32x4 x = *(const f32x4*)&vv[(b * 64 + row) * 128 + cc];
    *(f32x4*)&vbn[row][cc] = x * scs[row] + shs[row];
  }
  {  // stage edot[b]
    int idx = tid * 4;
    int j = idx >> 6, i = idx & 63;
    *(f32x4*)&edts[j][i] = *(const f32x4*)&edt[(b * 64 + j) * 64 + i];
  }
  __syncthreads();
  {  // ev3s[i] = dot(vbn[i], W3e) + evb3; 16 lanes per dot
    int i = tid >> 4, q = tid & 15;
    float d = 0.f;
#pragma unroll
    for (int u = 0; u < 8; ++u) d += vbn[i][q * 8 + u] * W3e[q * 8 + u];
    d += __shfl_xor(d, 1);
    d += __shfl_xor(d, 2);
    d += __shfl_xor(d, 4);
    d += __shfl_xor(d, 8);
    if (q == 0) ev3s[i] = d + evb3[0];
  }
  __syncthreads();
  {  // out_e + per-j partial sums
    int q = tid >> 6, j = tid & 63;  // q 0..15
    float s = 0.f;
    const float e3 = eb3[0];
    const float evj = ev3s[j];
#pragma unroll
    for (int r = 0; r < 4; ++r) {
      int i = q * 4 + r;
      float val = edts[j][i] + e3 + ev3s[i] + evj;
      out_e[(b * 64 + i) * 64 + j] = val;
      s += val;
    }
    pj[q][j] = s;
  }
  __syncthreads();
  {  // out_v[b,n] = pve3*vW[0] + dot(vbn[n], vW[1:129]) + vb
    int n = tid >> 4, q = tid & 15;
    float d = 0.f;
#pragma unroll
    for (int u = 0; u < 8; ++u) d += vbn[n][q * 8 + u] * vWs[1 + q * 8 + u];
    d += __shfl_xor(d, 1);
    d += __shfl_xor(d, 2);
    d += __shfl_xor(d, 4);
    d += __shfl_xor(d, 8);
    if (q == 0) {
      float p3 = 0.f;
#pragma unroll
      for (int qq = 0; qq < 16; ++qq) p3 += pj[qq][n];
      out_v[b * 64 + n] = d + p3 * vWs[0] + vb3[0];
    }
  }
}

extern "C" void kernel_launch(void* const* d_in, const int* in_sizes, int n_in,
                              void* d_out, int out_size, void* d_ws, size_t ws_size,
                              hipStream_t stream) {
  const float* in_v    = (const float*)d_in[0];
  const float* in_e    = (const float*)d_in[1];
  const float* bn_in_g = (const float*)d_in[2];
  const float* bn_in_b = (const float*)d_in[3];
  const float* g1_evW  = (const float*)d_in[4];
  const float* g1_evb  = (const float*)d_in[5];
  const float* g1_eW   = (const float*)d_in[6];
  const float* g1_eb   = (const float*)d_in[7];
  const float* g1_vW   = (const float*)d_in[8];
  const float* g1_vb   = (const float*)d_in[9];
  const float* inn_evW = (const float*)d_in[10];
  const float* inn_evb = (const float*)d_in[11];
  const float* inn_eW  = (const float*)d_in[12];
  const float* inn_eb  = (const float*)d_in[13];
  const float* inn_vW  = (const float*)d_in[14];
  const float* inn_vb  = (const float*)d_in[15];
  const float* bn_g    = (const float*)d_in[16];
  const float* bn_b    = (const float*)d_in[17];
  const float* g3_evW  = (const float*)d_in[18];
  const float* g3_evb  = (const float*)d_in[19];
  const float* g3_eW   = (const float*)d_in[20];
  const float* g3_eb   = (const float*)d_in[21];
  const float* g3_vW   = (const float*)d_in[22];
  const float* g3_vb   = (const float*)d_in[23];

  char* ws = (char*)d_ws;
  bf16_t* e_ws = (bf16_t*)(ws);                       // 64MB : e_t[b][j][i][c] bf16, swizzled tiles
  float* v     = (float*)(ws + 67108864);             // 2MB
  float* ev    = (float*)(ws + 69206016);             // 2MB
  float* pve   = (float*)(ws + 71303168);             // 2MB
  float* v0    = (float*)(ws + 73400320);             // 512KB
  bf16_t* Wt   = (bf16_t*)(ws + 73924608);            // 128KB
  float* edt   = (float*)(ws + 74055680);             // 1MB : edot[b][j][i]
  float* stats = (float*)(ws + 75104256);             // 2KB (4 layers x 128 f32)

  float* out_v = (float*)d_out;          // [B,N,1] = 4096
  float* out_e = (float*)d_out + 4096;   // [B,N,N,1] = 262144

  k_prep<<<265, 256, 0, stream>>>(in_v, bn_in_g, bn_in_b, inn_eW, v0, Wt, stats);

  // ---- g1 ----
  k_ev<32><<<1024, 256, 0, stream>>>(v0, g1_evW, g1_evb, ev);
  k_edge_g1<<<2048, 256, 0, stream>>>(in_e, g1_eW, g1_eb, ev, e_ws, pve);
  k_vg1_ev<<<1024, 256, 0, stream>>>(pve, v0, g1_vW, g1_vb, inn_evW, inn_evb, v, ev);

  // ---- inner layers ----
  for (int l = 0; l < 4; ++l) {
    if (l > 0)
      k_evbn<<<1024, 256, 0, stream>>>(v, stats + (l - 1) * 128, bn_g + (l - 1) * 64,
                                       bn_b + (l - 1) * 64, inn_evW + l * 16384,
                                       inn_evb + l * 128, ev);
    if (l < 3)
      k_edge_inner<false><<<2048, 256, 0, stream>>>(e_ws, Wt + l * 16384,
          inn_eb + l * 128, ev, pve, g3_eW, edt);
    else
      k_edge_inner<true><<<2048, 256, 0, stream>>>(e_ws, Wt + l * 16384,
          inn_eb + l * 128, ev, pve, g3_eW, edt);
    k_v_inner<<<1024, 256, 0, stream>>>(pve, v, inn_vW + l * 32768, inn_vb + l * 128,
                                        stats + l * 128);
  }

  // ---- g3 final (BN of layer 3 on the fly; pve3 in-block) ----
  k_g3<<<64, 1024, 0, stream>>>(v, stats + 384, bn_g + 192, bn_b + 192,
                                g3_evW, g3_evb, g3_eb, edt, g3_vW, g3_vb,
                                out_v, out_e);
}

// Round 2
// 402.630 us; speedup vs baseline: 1.0103x; 1.0103x over previous
//
#include <hip/hip_runtime.h>
#include <hip/hip_bf16.h>

// GraphVertEdgeNet on MI355X. B=64, N=64, VF=32, EF=16, DV=DE=128, LN=4.
// e stored bf16 in ws (64MB) in TRANSPOSED layout e_t[b][j][i][c]: every
// consumer accesses e by (b,j)-column across i, so this makes all edge-kernel
// HBM traffic fully contiguous streams.
// Round-2 change vs the 366us baseline: k_edge_inner split to ONE j-column
// per block (4096 blocks, 16KB tile, reg-staged, padded LDS) so more, smaller
// blocks co-reside per CU and their stage/compute/write phases interleave,
// filling the HBM idle gaps of the lockstep 2-col version.

typedef __bf16 bf16_t;
typedef __bf16 bf16x8 __attribute__((ext_vector_type(8)));
typedef __bf16 bf16x4 __attribute__((ext_vector_type(4)));
typedef float f32x4 __attribute__((ext_vector_type(4)));

// Barrier that does NOT drain vmcnt: safe when cross-wave deps are LDS-only.
__device__ __forceinline__ void bar_lgkm() {
  asm volatile("s_waitcnt lgkmcnt(0)\n\ts_barrier" ::: "memory");
}

// ---------------- prep: input BN (v0), Wt transpose, zero stats ----------------
__global__ __launch_bounds__(256) void k_prep(const float* __restrict__ vin,
    const float* __restrict__ g, const float* __restrict__ bt,
    const float* __restrict__ eW, float* __restrict__ v0,
    bf16_t* __restrict__ Wt, float* __restrict__ stats) {
  const int blk = blockIdx.x, tid = threadIdx.x;
  if (blk < 8) {  // BatchNorm1d(N*VF) over batch, ch = 0..2047
    int ch = blk * 256 + tid;
    float s = 0.f, s2 = 0.f;
    for (int b = 0; b < 64; ++b) { float x = vin[b * 2048 + ch]; s += x; s2 += x * x; }
    float mu = s * (1.f / 64.f);
    float var = s2 * (1.f / 64.f) - mu * mu;  // biased var
    float sc = rsqrtf(var + 1e-5f) * g[ch];
    float bb = bt[ch];
    for (int b = 0; b < 64; ++b) {
      float x = vin[b * 2048 + ch];
      v0[b * 2048 + ch] = (x - mu) * sc + bb;
    }
  } else if (blk < 264) {  // Wt[l][n][k] = eW[l][k][n] as bf16
    int idx = (blk - 8) * 256 + tid;  // 4*128*128 = 65536
    int l = idx >> 14, r = idx & 16383, n = r >> 7, k = r & 127;
    Wt[idx] = (bf16_t)eW[(l << 14) + (k << 7) + n];
  } else {  // zero stats (512 f32)
    for (int i = tid; i < 512; i += 256) stats[i] = 0.f;
  }
}

// ------------- ev = v_in @ W + bias : [4096,K]@[K,128]. 256 thr, 8 rows/blk -------------
template <int K>
__global__ __launch_bounds__(256) void k_ev(const float* __restrict__ v_in,
    const float* __restrict__ W, const float* __restrict__ bias,
    float* __restrict__ out) {
  __shared__ float rows_s[8][K];
  const int r0 = blockIdx.x * 8;
  const int tid = threadIdx.x;
  const int c = tid & 127, h = tid >> 7;  // h: rows h*4 .. h*4+3
  for (int idx = tid; idx < 8 * K; idx += 256) {
    int rr = idx / K, kk = idx % K;
    rows_s[rr][kk] = v_in[(r0 + rr) * K + kk];
  }
  __syncthreads();
  float acc[4];
  const float bv = bias[c];
#pragma unroll
  for (int r = 0; r < 4; ++r) acc[r] = bv;
  for (int k4 = 0; k4 < K; k4 += 4) {
    float w0 = W[(k4 + 0) * 128 + c], w1 = W[(k4 + 1) * 128 + c];
    float w2 = W[(k4 + 2) * 128 + c], w3 = W[(k4 + 3) * 128 + c];
#pragma unroll
    for (int r = 0; r < 4; ++r) {
      float4 x = *(const float4*)&rows_s[h * 4 + r][k4];
      acc[r] += x.x * w0 + x.y * w1 + x.z * w2 + x.w * w3;
    }
  }
#pragma unroll
  for (int r = 0; r < 4; ++r) out[(r0 + h * 4 + r) * 128 + c] = acc[r];
}

// ------------- fused BN(prev) + ev matmul (in-place v normalize). 256 thr -------------
__global__ __launch_bounds__(256) void k_evbn(float* __restrict__ v,
    const float* __restrict__ stats, const float* __restrict__ g,
    const float* __restrict__ bt, const float* __restrict__ W,
    const float* __restrict__ bias, float* __restrict__ out) {
  __shared__ float rows_s[8][128];
  const int r0 = blockIdx.x * 8;
  const int tid = threadIdx.x;
  const int c = tid & 127, h = tid >> 7;
#pragma unroll
  for (int u = 0; u < 4; ++u) {
    int idx = u * 256 + tid;
    int rr = idx >> 7, k = idx & 127;
    int n = (r0 + rr) & 63;
    float mu = stats[n] * (1.f / 8192.f);
    float var = stats[64 + n] * (1.f / 8192.f) - mu * mu;
    float sc = rsqrtf(var + 128.f) * g[n];
    float x = (v[(r0 + rr) * 128 + k] - mu) * sc + bt[n];
    rows_s[rr][k] = x;
    v[(r0 + rr) * 128 + k] = x;  // normalized v for residual/concat
  }
  __syncthreads();
  float acc[4];
  const float bv = bias[c];
#pragma unroll
  for (int r = 0; r < 4; ++r) acc[r] = bv;
  for (int k4 = 0; k4 < 128; k4 += 4) {
    float w0 = W[(k4 + 0) * 128 + c], w1 = W[(k4 + 1) * 128 + c];
    float w2 = W[(k4 + 2) * 128 + c], w3 = W[(k4 + 3) * 128 + c];
#pragma unroll
    for (int r = 0; r < 4; ++r) {
      float4 x = *(const float4*)&rows_s[h * 4 + r][k4];
      acc[r] += x.x * w0 + x.y * w1 + x.z * w2 + x.w * w3;
    }
  }
#pragma unroll
  for (int r = 0; r < 4; ++r) out[(r0 + h * 4 + r) * 128 + c] = acc[r];
}

// ------------- g1 edge pass (MFMA, K 16->32 zero-pad, 2 j/block) -------------
// Writes e_t[b][j][i][c] (transposed layout): fully contiguous 32KB per block.
__global__ __launch_bounds__(256) void k_edge_g1(const float* __restrict__ e0,
    const float* __restrict__ eW, const float* __restrict__ eb,
    const float* __restrict__ ev, bf16_t* __restrict__ e_ws,
    float* __restrict__ pve) {
  __shared__ bf16_t A0s[2][64][40];
  __shared__ bf16_t Os[2][64][136];
  const int b = blockIdx.x >> 5, j0 = (blockIdx.x & 31) * 2;
  const int tid = threadIdx.x;
  const int lane = tid & 63, w = tid >> 6;
  const int quad = lane >> 4, l16 = lane & 15;
#pragma unroll
  for (int t = 0; t < 2; ++t) {
    int idx = tid + t * 256;
    int row = idx >> 3, off = (idx & 7) * 4;
    int jc = off >> 4, k = off & 15;
    f32x4 x = *(const f32x4*)&e0[((b * 64 + row) * 64 + j0) * 16 + off];
    bf16x4 y;
#pragma unroll
    for (int r = 0; r < 4; ++r) y[r] = (bf16_t)x[r];
    *(bf16x4*)&A0s[jc][row][k] = y;
    bf16x4 z = {(bf16_t)0.f, (bf16_t)0.f, (bf16_t)0.f, (bf16_t)0.f};
    *(bf16x4*)&A0s[jc][row][16 + k] = z;
  }
  const int c0[2] = {w * 32 + quad * 4, w * 32 + 16 + quad * 4};
  bf16x8 wf[2];
#pragma unroll
  for (int nt = 0; nt < 2; ++nt) {
    const int c = w * 32 + nt * 16 + l16;
#pragma unroll
    for (int jj = 0; jj < 8; ++jj)
      wf[nt][jj] = (quad < 2) ? (bf16_t)eW[(quad * 8 + jj) * 128 + c] : (bf16_t)0.f;
  }
  f32x4 acc[2][4][2];
  {
    f32x4 ebv[2], evj[2][2], evi[4][2];
#pragma unroll
    for (int nt = 0; nt < 2; ++nt) {
      ebv[nt] = *(const f32x4*)&eb[c0[nt]];
#pragma unroll
      for (int jc = 0; jc < 2; ++jc)
        evj[jc][nt] = *(const f32x4*)&ev[(b * 64 + j0 + jc) * 128 + c0[nt]];
#pragma unroll
      for (int mt = 0; mt < 4; ++mt)
        evi[mt][nt] = *(const f32x4*)&ev[(b * 64 + mt * 16 + l16) * 128 + c0[nt]];
    }
#pragma unroll
    for (int jc = 0; jc < 2; ++jc)
#pragma unroll
      for (int mt = 0; mt < 4; ++mt)
#pragma unroll
        for (int nt = 0; nt < 2; ++nt)
          acc[jc][mt][nt] = ebv[nt] + evj[jc][nt] + evi[mt][nt];
  }
  __syncthreads();
#pragma unroll
  for (int jc = 0; jc < 2; ++jc) {
#pragma unroll
    for (int mt = 0; mt < 4; ++mt) {
      bf16x8 ef = *(const bf16x8*)&A0s[jc][mt * 16 + l16][quad * 8];
#pragma unroll
      for (int nt = 0; nt < 2; ++nt)
        acc[jc][mt][nt] = __builtin_amdgcn_mfma_f32_16x16x32_bf16(wf[nt], ef, acc[jc][mt][nt], 0, 0, 0);
    }
  }
#pragma unroll
  for (int jc = 0; jc < 2; ++jc) {
#pragma unroll
    for (int nt = 0; nt < 2; ++nt) {
      f32x4 ps = {0.f, 0.f, 0.f, 0.f};
#pragma unroll
      for (int mt = 0; mt < 4; ++mt) {
        const int i = mt * 16 + l16;
        bf16x4 outv;
#pragma unroll
        for (int r = 0; r < 4; ++r) {
          float vv = fmaxf(acc[jc][mt][nt][r], 0.f);
          ps[r] += vv;
          outv[r] = (bf16_t)vv;
        }
        *(bf16x4*)&Os[jc][i][c0[nt]] = outv;
      }
#pragma unroll
      for (int m = 1; m <= 8; m <<= 1) {
#pragma unroll
        for (int r = 0; r < 4; ++r) ps[r] += __shfl_xor(ps[r], m);
      }
      if (l16 == 0) *(f32x4*)&pve[(b * 64 + j0 + jc) * 128 + c0[nt]] = ps;
    }
  }
  __syncthreads();
  {  // contiguous 32KB copy-out to transposed layout
    bf16_t* ebase = &e_ws[((size_t)(b * 64 + j0) * 64) * 128];
#pragma unroll
    for (int t = 0; t < 8; ++t) {
      int idx = tid + t * 256;
      *(int4*)&ebase[idx * 8] =
          *(const int4*)&Os[idx >> 10][(idx >> 4) & 63][(idx & 15) * 8];
    }
  }
}

// ------------- fused g1-v + layer0-ev. 256 thr, 8 rows/blk -------------
__global__ __launch_bounds__(256) void k_vg1_ev(const float* __restrict__ pve,
    const float* __restrict__ v0, const float* __restrict__ vW,
    const float* __restrict__ vb, const float* __restrict__ evW,
    const float* __restrict__ evb, float* __restrict__ v, float* __restrict__ ev) {
  __shared__ float in_s[8][160];
  __shared__ float vr[8][128];
  const int r0 = blockIdx.x * 8;
  const int tid = threadIdx.x;
  const int c = tid & 127, h = tid >> 7;
#pragma unroll
  for (int u = 0; u < 4; ++u) {
    int idx = u * 256 + tid;
    int rr = idx >> 7, k = idx & 127;
    in_s[rr][k] = pve[(r0 + rr) * 128 + k];
  }
  {
    int rr = tid >> 5, k = tid & 31;
    in_s[rr][128 + k] = v0[(r0 + rr) * 32 + k];
  }
  __syncthreads();
  float acc[4];
  const float bv = vb[c];
#pragma unroll
  for (int r = 0; r < 4; ++r) acc[r] = bv;
  for (int k4 = 0; k4 < 160; k4 += 4) {
    float w0 = vW[(k4 + 0) * 128 + c], w1 = vW[(k4 + 1) * 128 + c];
    float w2 = vW[(k4 + 2) * 128 + c], w3 = vW[(k4 + 3) * 128 + c];
#pragma unroll
    for (int r = 0; r < 4; ++r) {
      float4 x = *(const float4*)&in_s[h * 4 + r][k4];
      acc[r] += x.x * w0 + x.y * w1 + x.z * w2 + x.w * w3;
    }
  }
#pragma unroll
  for (int r = 0; r < 4; ++r) {
    float val = fmaxf(acc[r], 0.f);
    vr[h * 4 + r][c] = val;
    v[(r0 + h * 4 + r) * 128 + c] = val;
  }
  __syncthreads();
  float acc2[4];
  const float bv2 = evb[c];
#pragma unroll
  for (int r = 0; r < 4; ++r) acc2[r] = bv2;
  for (int k4 = 0; k4 < 128; k4 += 4) {
    float w0 = evW[(k4 + 0) * 128 + c], w1 = evW[(k4 + 1) * 128 + c];
    float w2 = evW[(k4 + 2) * 128 + c], w3 = evW[(k4 + 3) * 128 + c];
#pragma unroll
    for (int r = 0; r < 4; ++r) {
      float4 x = *(const float4*)&vr[h * 4 + r][k4];
      acc2[r] += x.x * w0 + x.y * w1 + x.z * w2 + x.w * w3;
    }
  }
#pragma unroll
  for (int r = 0; r < 4; ++r) ev[(r0 + h * 4 + r) * 128 + c] = acc2[r];
}

// ------------- inner edge pass: 4096 blocks x 1 j-col, reg-staged, lgkm barriers -------------
// e_t[b][j][i][c] transposed layout: block (b,j) reads/writes one contiguous
// 16KB region. e += relu(e@W + eb + ev_i + ev_j); pve = pre-residual col sums.
// LAST: instead of e write-back, computes edot[b][j][i] = dot(e_new[b,i,j,:], eW3).
template <bool LAST>
__global__ __launch_bounds__(256) void k_edge_inner(bf16_t* __restrict__ e_ws,
    const bf16_t* __restrict__ Wt, const float* __restrict__ eb,
    const float* __restrict__ ev, float* __restrict__ pve,
    const float* __restrict__ eW3, float* __restrict__ edt) {
  __shared__ bf16_t As[64][136];   // [i][c], +8 pad
  __shared__ float W3s[128];
  const int b = blockIdx.x >> 6, j = blockIdx.x & 63;
  const int tid = threadIdx.x;
  const int lane = tid & 63, w = tid >> 6;
  const int quad = lane >> 4, l16 = lane & 15;
  bf16_t* ebase = &e_ws[((size_t)(b * 64 + j) * 64) * 128];
  // stage 1 e column: one contiguous 16KB stream
  int4 stg[4];
#pragma unroll
  for (int t = 0; t < 4; ++t) {
    int idx = tid + t * 256;
    stg[t] = *(const int4*)&ebase[idx * 8];
  }
  if (LAST) {
    if (tid < 128) W3s[tid] = eW3[tid];
  }
  // W A-frags in registers (L2-hot): A[m=c][k]
  bf16x8 wf[2][4];
#pragma unroll
  for (int nt = 0; nt < 2; ++nt)
#pragma unroll
    for (int ks = 0; ks < 4; ++ks)
      wf[nt][ks] = *(const bf16x8*)&Wt[(w * 32 + nt * 16 + l16) * 128 + ks * 32 + quad * 8];
  const int c0[2] = {w * 32 + quad * 4, w * 32 + 16 + quad * 4};
  // acc init = eb + ev_j + ev_i (pre-barrier loads)
  f32x4 acc[4][2];
  {
    f32x4 ebv[2], evj[2], evi[4][2];
#pragma unroll
    for (int nt = 0; nt < 2; ++nt) {
      ebv[nt] = *(const f32x4*)&eb[c0[nt]];
      evj[nt] = *(const f32x4*)&ev[(b * 64 + j) * 128 + c0[nt]];
#pragma unroll
      for (int mt = 0; mt < 4; ++mt)
        evi[mt][nt] = *(const f32x4*)&ev[(b * 64 + mt * 16 + l16) * 128 + c0[nt]];
    }
#pragma unroll
    for (int mt = 0; mt < 4; ++mt)
#pragma unroll
      for (int nt = 0; nt < 2; ++nt)
        acc[mt][nt] = ebv[nt] + evj[nt] + evi[mt][nt];
  }
#pragma unroll
  for (int t = 0; t < 4; ++t) {
    int idx = tid + t * 256;
    *(int4*)&As[idx >> 4][(idx & 15) * 8] = stg[t];
  }
  bar_lgkm();
  // MFMA: D[c][i] = sum_k Wt[c][k] * e[i][k]  (32 MFMA per wave)
#pragma unroll
  for (int ks = 0; ks < 4; ++ks) {
    bf16x8 ef[4];
#pragma unroll
    for (int mt = 0; mt < 4; ++mt)
      ef[mt] = *(const bf16x8*)&As[mt * 16 + l16][ks * 32 + quad * 8];
#pragma unroll
    for (int mt = 0; mt < 4; ++mt)
#pragma unroll
      for (int nt = 0; nt < 2; ++nt)
        acc[mt][nt] = __builtin_amdgcn_mfma_f32_16x16x32_bf16(wf[nt][ks], ef[mt], acc[mt][nt], 0, 0, 0);
  }
  bar_lgkm();  // all MFMA frag reads of As done (LDS-only dep)
  // epilogue: relu, pve, residual from LDS, packed b64 writes to own cells
#pragma unroll
  for (int nt = 0; nt < 2; ++nt) {
    f32x4 ps = {0.f, 0.f, 0.f, 0.f};
#pragma unroll
    for (int mt = 0; mt < 4; ++mt) {
      const int i = mt * 16 + l16;
      bf16x4 eo = *(const bf16x4*)&As[i][c0[nt]];
      bf16x4 outv;
#pragma unroll
      for (int r = 0; r < 4; ++r) {
        float vv = fmaxf(acc[mt][nt][r], 0.f);
        ps[r] += vv;                            // pve is pre-residual
        outv[r] = (bf16_t)(vv + (float)eo[r]);  // residual
      }
      *(bf16x4*)&As[i][c0[nt]] = outv;
    }
#pragma unroll
    for (int m = 1; m <= 8; m <<= 1) {  // reduce over i (l16 lanes)
#pragma unroll
      for (int r = 0; r < 4; ++r) ps[r] += __shfl_xor(ps[r], m);
    }
    if (l16 == 0) *(f32x4*)&pve[(b * 64 + j) * 128 + c0[nt]] = ps;
  }
  bar_lgkm();  // As fully updated (LDS-only dep)
  if (!LAST) {
    // contiguous 16KB write-back
#pragma unroll
    for (int t = 0; t < 4; ++t) {
      int idx = tid + t * 256;
      *(int4*)&ebase[idx * 8] = *(const int4*)&As[idx >> 4][(idx & 15) * 8];
    }
  } else {
    // edot[b][j][i] = dot(e_new[b,i,j,:], W3)
    const int i = tid >> 2, q = tid & 3;
    float d = 0.f;
#pragma unroll
    for (int t = 0; t < 4; ++t) {
      bf16x8 x = *(const bf16x8*)&As[i][q * 32 + t * 8];
#pragma unroll
      for (int u = 0; u < 8; ++u) d += (float)x[u] * W3s[q * 32 + t * 8 + u];
    }
    d += __shfl_xor(d, 1);
    d += __shfl_xor(d, 2);
    if (q == 0) edt[(b * 64 + j) * 64 + i] = d;
  }
}

// ------------- inner v pass: v = relu(concat(pve,v)@[256,128]+vb) + v; BN stats. 256 thr -------------
__global__ __launch_bounds__(256) void k_v_inner(const float* __restrict__ pve,
    float* __restrict__ v, const float* __restrict__ vW,
    const float* __restrict__ vb, float* __restrict__ stats) {
  __shared__ float in_s[8][256];
  __shared__ float outs[8][132];  // +4 pad
  __shared__ float part[16][2];
  const int r0 = blockIdx.x * 8;
  const int tid = threadIdx.x;
  const int c = tid & 127, h = tid >> 7;
#pragma unroll
  for (int u = 0; u < 4; ++u) {
    int idx = u * 256 + tid;
    int rr = idx >> 7, k = idx & 127;
    in_s[rr][k] = pve[(r0 + rr) * 128 + k];
    in_s[rr][128 + k] = v[(r0 + rr) * 128 + k];
  }
  __syncthreads();
  float acc[4];
  const float bv = vb[c];
#pragma unroll
  for (int r = 0; r < 4; ++r) acc[r] = bv;
  for (int k4 = 0; k4 < 256; k4 += 4) {
    float w0 = vW[(k4 + 0) * 128 + c], w1 = vW[(k4 + 1) * 128 + c];
    float w2 = vW[(k4 + 2) * 128 + c], w3 = vW[(k4 + 3) * 128 + c];
#pragma unroll
    for (int r = 0; r < 4; ++r) {
      float4 x = *(const float4*)&in_s[h * 4 + r][k4];
      acc[r] += x.x * w0 + x.y * w1 + x.z * w2 + x.w * w3;
    }
  }
#pragma unroll
  for (int r = 0; r < 4; ++r) {
    float val = fmaxf(acc[r], 0.f) + in_s[h * 4 + r][128 + c];  // relu + residual
    outs[h * 4 + r][c] = val;
    v[(r0 + h * 4 + r) * 128 + c] = val;
  }
  __syncthreads();
  if (tid < 16) {  // parallel BN-stat partial reduction
    int rr = tid >> 1, half = tid & 1;
    float s = 0.f, s2 = 0.f;
    for (int k = 0; k < 64; ++k) {
      float x = outs[rr][half * 64 + k];
      s += x; s2 += x * x;
    }
    part[tid][0] = s;
    part[tid][1] = s2;
  }
  __syncthreads();
  if (tid < 8) {
    int n = (r0 + tid) & 63;
    atomicAdd(&stats[n], part[tid * 2][0] + part[tid * 2 + 1][0]);
    atomicAdd(&stats[64 + n], part[tid * 2][1] + part[tid * 2 + 1][1]);
  }
}

// ------------- g3 final: per-b block. BN(v), ev3, out_e = edot+eb3+ev3_i+ev3_j,
// pve3 in LDS, out_v. One kernel, 64 blocks. -------------
__global__ __launch_bounds__(256) void k_g3(const float* __restrict__ vv,
    const float* __restrict__ stats3, const float* __restrict__ g,
    const float* __restrict__ bt, const float* __restrict__ evW3,
    const float* __restrict__ evb3, const float* __restrict__ eb3,
    const float* __restrict__ edt, const float* __restrict__ vW3,
    const float* __restrict__ vb3, float* __restrict__ out_v,
    float* __restrict__ out_e) {
  __shared__ float vbn[64][132];   // +4 pad
  __shared__ float edts[64][68];   // edt[b][j][i], +4 pad
  __shared__ float scs[64], shs[64];
  __shared__ float W3e[128];
  __shared__ float vWs[132];
  __shared__ float ev3s[64];
  __shared__ float pj[4][64];
  const int b = blockIdx.x, tid = threadIdx.x;
  if (tid < 64) {
    float mu = stats3[tid] * (1.f / 8192.f);
    float var = stats3[64 + tid] * (1.f / 8192.f) - mu * mu;
    float sc = rsqrtf(var + 128.f) * g[tid];
    scs[tid] = sc;
    shs[tid] = bt[tid] - mu * sc;
  }
  if (tid < 128) W3e[tid] = evW3[tid];
  if (tid < 129) vWs[tid] = vW3[tid];
  __syncthreads();
#pragma unroll
  for (int t = 0; t < 8; ++t) {  // stage BN(v[b])
    int idx = t * 1024 + tid * 4;
    int row = idx >> 7, cc = idx & 127;
    f32x4 x = *(const f32x4*)&vv[(b * 64 + row) * 128 + cc];
    *(f32x4*)&vbn[row][cc] = x * scs[row] + shs[row];
  }
#pragma unroll
  for (int t = 0; t < 4; ++t) {  // stage edot[b]
    int idx = t * 1024 + tid * 4;
    int j = idx >> 6, i = idx & 63;
    *(f32x4*)&edts[j][i] = *(const f32x4*)&edt[(b * 64 + j) * 64 + i];
  }
  __syncthreads();
  {  // ev3s[i] = dot(vbn[i], W3e) + evb3
    int i = tid >> 2, q = tid & 3;
    float d = 0.f;
#pragma unroll
    for (int u = 0; u < 32; ++u) d += vbn[i][q * 32 + u] * W3e[q * 32 + u];
    d += __shfl_xor(d, 1);
    d += __shfl_xor(d, 2);
    if (q == 0) ev3s[i] = d + evb3[0];
  }
  __syncthreads();
  {  // out_e + per-j partial sums
    int q = tid >> 6, j = tid & 63;
    float s = 0.f;
    const float e3 = eb3[0];
    const float evj = ev3s[j];
#pragma unroll
    for (int r = 0; r < 16; ++r) {
      int i = q * 16 + r;
      float val = edts[j][i] + e3 + ev3s[i] + evj;
      out_e[(b * 64 + i) * 64 + j] = val;
      s += val;
    }
    pj[q][j] = s;
  }
  __syncthreads();
  {  // out_v[b,n] = pve3*vW[0] + dot(vbn[n], vW[1:129]) + vb
    int n = tid >> 2, q = tid & 3;
    float d = 0.f;
#pragma unroll
    for (int u = 0; u < 32; ++u) d += vbn[n][q * 32 + u] * vWs[1 + q * 32 + u];
    d += __shfl_xor(d, 1);
    d += __shfl_xor(d, 2);
    if (q == 0) {
      float p3 = pj[0][n] + pj[1][n] + pj[2][n] + pj[3][n];
      out_v[b * 64 + n] = d + p3 * vWs[0] + vb3[0];
    }
  }
}

extern "C" void kernel_launch(void* const* d_in, const int* in_sizes, int n_in,
                              void* d_out, int out_size, void* d_ws, size_t ws_size,
                              hipStream_t stream) {
  const float* in_v    = (const float*)d_in[0];
  const float* in_e    = (const float*)d_in[1];
  const float* bn_in_g = (const float*)d_in[2];
  const float* bn_in_b = (const float*)d_in[3];
  const float* g1_evW  = (const float*)d_in[4];
  const float* g1_evb  = (const float*)d_in[5];
  const float* g1_eW   = (const float*)d_in[6];
  const float* g1_eb   = (const float*)d_in[7];
  const float* g1_vW   = (const float*)d_in[8];
  const float* g1_vb   = (const float*)d_in[9];
  const float* inn_evW = (const float*)d_in[10];
  const float* inn_evb = (const float*)d_in[11];
  const float* inn_eW  = (const float*)d_in[12];
  const float* inn_eb  = (const float*)d_in[13];
  const float* inn_vW  = (const float*)d_in[14];
  const float* inn_vb  = (const float*)d_in[15];
  const float* bn_g    = (const float*)d_in[16];
  const float* bn_b    = (const float*)d_in[17];
  const float* g3_evW  = (const float*)d_in[18];
  const float* g3_evb  = (const float*)d_in[19];
  const float* g3_eW   = (const float*)d_in[20];
  const float* g3_eb   = (const float*)d_in[21];
  const float* g3_vW   = (const float*)d_in[22];
  const float* g3_vb   = (const float*)d_in[23];

  char* ws = (char*)d_ws;
  bf16_t* e_ws = (bf16_t*)(ws);                       // 64MB : e_t[b][j][i][c] bf16
  float* v     = (float*)(ws + 67108864);             // 2MB
  float* ev    = (float*)(ws + 69206016);             // 2MB
  float* pve   = (float*)(ws + 71303168);             // 2MB
  float* v0    = (float*)(ws + 73400320);             // 512KB
  bf16_t* Wt   = (bf16_t*)(ws + 73924608);            // 128KB
  float* edt   = (float*)(ws + 74055680);             // 1MB : edot[b][j][i]
  float* stats = (float*)(ws + 75104256);             // 2KB (4 layers x 128 f32)

  float* out_v = (float*)d_out;          // [B,N,1] = 4096
  float* out_e = (float*)d_out + 4096;   // [B,N,N,1] = 262144

  k_prep<<<265, 256, 0, stream>>>(in_v, bn_in_g, bn_in_b, inn_eW, v0, Wt, stats);

  // ---- g1 ----
  k_ev<32><<<512, 256, 0, stream>>>(v0, g1_evW, g1_evb, ev);
  k_edge_g1<<<2048, 256, 0, stream>>>(in_e, g1_eW, g1_eb, ev, e_ws, pve);
  k_vg1_ev<<<512, 256, 0, stream>>>(pve, v0, g1_vW, g1_vb, inn_evW, inn_evb, v, ev);

  // ---- inner layers ----
  for (int l = 0; l < 4; ++l) {
    if (l > 0)
      k_evbn<<<512, 256, 0, stream>>>(v, stats + (l - 1) * 128, bn_g + (l - 1) * 64,
                                      bn_b + (l - 1) * 64, inn_evW + l * 16384,
                                      inn_evb + l * 128, ev);
    if (l < 3)
      k_edge_inner<false><<<4096, 256, 0, stream>>>(e_ws, Wt + l * 16384,
          inn_eb + l * 128, ev, pve, g3_eW, edt);
    else
      k_edge_inner<true><<<4096, 256, 0, stream>>>(e_ws, Wt + l * 16384,
          inn_eb + l * 128, ev, pve, g3_eW, edt);
    k_v_inner<<<512, 256, 0, stream>>>(pve, v, inn_vW + l * 32768, inn_vb + l * 128,
                                       stats + l * 128);
  }

  // ---- g3 final (BN of layer 3 on the fly; pve3 in-block) ----
  k_g3<<<64, 256, 0, stream>>>(v, stats + 384, bn_g + 192, bn_b + 192,
                               g3_evW, g3_evb, g3_eb, edt, g3_vW, g3_vb,
                               out_v, out_e);
}

// Round 3
// 383.893 us; speedup vs baseline: 1.0596x; 1.0488x over previous
//
#include <hip/hip_runtime.h>
#include <hip/hip_bf16.h>

// GraphVertEdgeNet on MI355X. B=64, N=64, VF=32, EF=16, DV=DE=128, LN=4.
// e stored bf16 in ws (64MB) in TRANSPOSED layout e_t[b][j][i][c]: every
// consumer accesses e by (b,j)-column across i, making all edge-kernel
// HBM traffic fully contiguous 32KB streams.
// Round-3: recombination of measured winners.
//   - edge kernels: round-0 form (2 j-cols/block, reg-staged, padded LDS,
//     2048 blocks) — best measured (~36us); gload_lds-swizzle and 1-col
//     variants both regressed (-20%/-24%).
//   - small matmul kernels: round-1 form (1024 blocks x 4 rows = 4 blk/CU,
//     k_g3 at 1024 threads) — measured ~23us faster in aggregate.

typedef __bf16 bf16_t;
typedef __bf16 bf16x8 __attribute__((ext_vector_type(8)));
typedef __bf16 bf16x4 __attribute__((ext_vector_type(4)));
typedef float f32x4 __attribute__((ext_vector_type(4)));

// Barrier that does NOT drain vmcnt: safe when cross-wave deps are LDS-only.
__device__ __forceinline__ void bar_lgkm() {
  asm volatile("s_waitcnt lgkmcnt(0)\n\ts_barrier" ::: "memory");
}

// ---------------- prep: input BN (v0), Wt transpose, zero stats ----------------
__global__ __launch_bounds__(256) void k_prep(const float* __restrict__ vin,
    const float* __restrict__ g, const float* __restrict__ bt,
    const float* __restrict__ eW, float* __restrict__ v0,
    bf16_t* __restrict__ Wt, float* __restrict__ stats) {
  const int blk = blockIdx.x, tid = threadIdx.x;
  if (blk < 8) {  // BatchNorm1d(N*VF) over batch, ch = 0..2047
    int ch = blk * 256 + tid;
    float s = 0.f, s2 = 0.f;
    for (int b = 0; b < 64; ++b) { float x = vin[b * 2048 + ch]; s += x; s2 += x * x; }
    float mu = s * (1.f / 64.f);
    float var = s2 * (1.f / 64.f) - mu * mu;  // biased var
    float sc = rsqrtf(var + 1e-5f) * g[ch];
    float bb = bt[ch];
    for (int b = 0; b < 64; ++b) {
      float x = vin[b * 2048 + ch];
      v0[b * 2048 + ch] = (x - mu) * sc + bb;
    }
  } else if (blk < 264) {  // Wt[l][n][k] = eW[l][k][n] as bf16
    int idx = (blk - 8) * 256 + tid;  // 4*128*128 = 65536
    int l = idx >> 14, r = idx & 16383, n = r >> 7, k = r & 127;
    Wt[idx] = (bf16_t)eW[(l << 14) + (k << 7) + n];
  } else {  // zero stats (512 f32)
    for (int i = tid; i < 512; i += 256) stats[i] = 0.f;
  }
}

// ------------- ev = v_in @ W + bias : [4096,K]@[K,128]. 256 thr, 4 rows/blk -------------
template <int K>
__global__ __launch_bounds__(256) void k_ev(const float* __restrict__ v_in,
    const float* __restrict__ W, const float* __restrict__ bias,
    float* __restrict__ out) {
  __shared__ float rows_s[4][K];
  const int r0 = blockIdx.x * 4;
  const int tid = threadIdx.x;
  const int c = tid & 127, h = tid >> 7;  // h: rows h*2 .. h*2+1
  for (int idx = tid; idx < 4 * K; idx += 256) {
    int rr = idx / K, kk = idx % K;
    rows_s[rr][kk] = v_in[(r0 + rr) * K + kk];
  }
  __syncthreads();
  float acc[2];
  const float bv = bias[c];
  acc[0] = bv; acc[1] = bv;
  for (int k4 = 0; k4 < K; k4 += 4) {
    float w0 = W[(k4 + 0) * 128 + c], w1 = W[(k4 + 1) * 128 + c];
    float w2 = W[(k4 + 2) * 128 + c], w3 = W[(k4 + 3) * 128 + c];
#pragma unroll
    for (int r = 0; r < 2; ++r) {
      float4 x = *(const float4*)&rows_s[h * 2 + r][k4];
      acc[r] += x.x * w0 + x.y * w1 + x.z * w2 + x.w * w3;
    }
  }
#pragma unroll
  for (int r = 0; r < 2; ++r) out[(r0 + h * 2 + r) * 128 + c] = acc[r];
}

// ------------- fused BN(prev) + ev matmul (in-place v normalize). 4 rows/blk -------------
__global__ __launch_bounds__(256) void k_evbn(float* __restrict__ v,
    const float* __restrict__ stats, const float* __restrict__ g,
    const float* __restrict__ bt, const float* __restrict__ W,
    const float* __restrict__ bias, float* __restrict__ out) {
  __shared__ float rows_s[4][128];
  const int r0 = blockIdx.x * 4;
  const int tid = threadIdx.x;
  const int c = tid & 127, h = tid >> 7;
#pragma unroll
  for (int u = 0; u < 2; ++u) {
    int idx = u * 256 + tid;
    int rr = idx >> 7, k = idx & 127;
    int n = (r0 + rr) & 63;
    float mu = stats[n] * (1.f / 8192.f);
    float var = stats[64 + n] * (1.f / 8192.f) - mu * mu;
    float sc = rsqrtf(var + 128.f) * g[n];
    float x = (v[(r0 + rr) * 128 + k] - mu) * sc + bt[n];
    rows_s[rr][k] = x;
    v[(r0 + rr) * 128 + k] = x;  // normalized v for residual/concat
  }
  __syncthreads();
  float acc[2];
  const float bv = bias[c];
  acc[0] = bv; acc[1] = bv;
  for (int k4 = 0; k4 < 128; k4 += 4) {
    float w0 = W[(k4 + 0) * 128 + c], w1 = W[(k4 + 1) * 128 + c];
    float w2 = W[(k4 + 2) * 128 + c], w3 = W[(k4 + 3) * 128 + c];
#pragma unroll
    for (int r = 0; r < 2; ++r) {
      float4 x = *(const float4*)&rows_s[h * 2 + r][k4];
      acc[r] += x.x * w0 + x.y * w1 + x.z * w2 + x.w * w3;
    }
  }
#pragma unroll
  for (int r = 0; r < 2; ++r) out[(r0 + h * 2 + r) * 128 + c] = acc[r];
}

// ------------- g1 edge pass (MFMA, K 16->32 zero-pad, 2 j/block) -------------
// Writes e_t[b][j][i][c] (transposed layout): fully contiguous 32KB per block.
__global__ __launch_bounds__(256) void k_edge_g1(const float* __restrict__ e0,
    const float* __restrict__ eW, const float* __restrict__ eb,
    const float* __restrict__ ev, bf16_t* __restrict__ e_ws,
    float* __restrict__ pve) {
  __shared__ bf16_t A0s[2][64][40];
  __shared__ bf16_t Os[2][64][136];
  const int b = blockIdx.x >> 5, j0 = (blockIdx.x & 31) * 2;
  const int tid = threadIdx.x;
  const int lane = tid & 63, w = tid >> 6;
  const int quad = lane >> 4, l16 = lane & 15;
#pragma unroll
  for (int t = 0; t < 2; ++t) {
    int idx = tid + t * 256;
    int row = idx >> 3, off = (idx & 7) * 4;
    int jc = off >> 4, k = off & 15;
    f32x4 x = *(const f32x4*)&e0[((b * 64 + row) * 64 + j0) * 16 + off];
    bf16x4 y;
#pragma unroll
    for (int r = 0; r < 4; ++r) y[r] = (bf16_t)x[r];
    *(bf16x4*)&A0s[jc][row][k] = y;
    bf16x4 z = {(bf16_t)0.f, (bf16_t)0.f, (bf16_t)0.f, (bf16_t)0.f};
    *(bf16x4*)&A0s[jc][row][16 + k] = z;
  }
  const int c0[2] = {w * 32 + quad * 4, w * 32 + 16 + quad * 4};
  bf16x8 wf[2];
#pragma unroll
  for (int nt = 0; nt < 2; ++nt) {
    const int c = w * 32 + nt * 16 + l16;
#pragma unroll
    for (int jj = 0; jj < 8; ++jj)
      wf[nt][jj] = (quad < 2) ? (bf16_t)eW[(quad * 8 + jj) * 128 + c] : (bf16_t)0.f;
  }
  f32x4 acc[2][4][2];
  {
    f32x4 ebv[2], evj[2][2], evi[4][2];
#pragma unroll
    for (int nt = 0; nt < 2; ++nt) {
      ebv[nt] = *(const f32x4*)&eb[c0[nt]];
#pragma unroll
      for (int jc = 0; jc < 2; ++jc)
        evj[jc][nt] = *(const f32x4*)&ev[(b * 64 + j0 + jc) * 128 + c0[nt]];
#pragma unroll
      for (int mt = 0; mt < 4; ++mt)
        evi[mt][nt] = *(const f32x4*)&ev[(b * 64 + mt * 16 + l16) * 128 + c0[nt]];
    }
#pragma unroll
    for (int jc = 0; jc < 2; ++jc)
#pragma unroll
      for (int mt = 0; mt < 4; ++mt)
#pragma unroll
        for (int nt = 0; nt < 2; ++nt)
          acc[jc][mt][nt] = ebv[nt] + evj[jc][nt] + evi[mt][nt];
  }
  __syncthreads();
#pragma unroll
  for (int jc = 0; jc < 2; ++jc) {
#pragma unroll
    for (int mt = 0; mt < 4; ++mt) {
      bf16x8 ef = *(const bf16x8*)&A0s[jc][mt * 16 + l16][quad * 8];
#pragma unroll
      for (int nt = 0; nt < 2; ++nt)
        acc[jc][mt][nt] = __builtin_amdgcn_mfma_f32_16x16x32_bf16(wf[nt], ef, acc[jc][mt][nt], 0, 0, 0);
    }
  }
#pragma unroll
  for (int jc = 0; jc < 2; ++jc) {
#pragma unroll
    for (int nt = 0; nt < 2; ++nt) {
      f32x4 ps = {0.f, 0.f, 0.f, 0.f};
#pragma unroll
      for (int mt = 0; mt < 4; ++mt) {
        const int i = mt * 16 + l16;
        bf16x4 outv;
#pragma unroll
        for (int r = 0; r < 4; ++r) {
          float vv = fmaxf(acc[jc][mt][nt][r], 0.f);
          ps[r] += vv;
          outv[r] = (bf16_t)vv;
        }
        *(bf16x4*)&Os[jc][i][c0[nt]] = outv;
      }
#pragma unroll
      for (int m = 1; m <= 8; m <<= 1) {
#pragma unroll
        for (int r = 0; r < 4; ++r) ps[r] += __shfl_xor(ps[r], m);
      }
      if (l16 == 0) *(f32x4*)&pve[(b * 64 + j0 + jc) * 128 + c0[nt]] = ps;
    }
  }
  __syncthreads();
  {  // contiguous 32KB copy-out to transposed layout
    bf16_t* ebase = &e_ws[((size_t)(b * 64 + j0) * 64) * 128];
#pragma unroll
    for (int t = 0; t < 8; ++t) {
      int idx = tid + t * 256;
      *(int4*)&ebase[idx * 8] =
          *(const int4*)&Os[idx >> 10][(idx >> 4) & 63][(idx & 15) * 8];
    }
  }
}

// ------------- fused g1-v + layer0-ev. 256 thr, 4 rows/blk -------------
__global__ __launch_bounds__(256) void k_vg1_ev(const float* __restrict__ pve,
    const float* __restrict__ v0, const float* __restrict__ vW,
    const float* __restrict__ vb, const float* __restrict__ evW,
    const float* __restrict__ evb, float* __restrict__ v, float* __restrict__ ev) {
  __shared__ float in_s[4][160];
  __shared__ float vr[4][128];
  const int r0 = blockIdx.x * 4;
  const int tid = threadIdx.x;
  const int c = tid & 127, h = tid >> 7;
#pragma unroll
  for (int u = 0; u < 2; ++u) {
    int idx = u * 256 + tid;
    int rr = idx >> 7, k = idx & 127;
    in_s[rr][k] = pve[(r0 + rr) * 128 + k];
  }
  if (tid < 128) {
    int rr = tid >> 5, k = tid & 31;
    in_s[rr][128 + k] = v0[(r0 + rr) * 32 + k];
  }
  __syncthreads();
  float acc[2];
  const float bv = vb[c];
  acc[0] = bv; acc[1] = bv;
  for (int k4 = 0; k4 < 160; k4 += 4) {
    float w0 = vW[(k4 + 0) * 128 + c], w1 = vW[(k4 + 1) * 128 + c];
    float w2 = vW[(k4 + 2) * 128 + c], w3 = vW[(k4 + 3) * 128 + c];
#pragma unroll
    for (int r = 0; r < 2; ++r) {
      float4 x = *(const float4*)&in_s[h * 2 + r][k4];
      acc[r] += x.x * w0 + x.y * w1 + x.z * w2 + x.w * w3;
    }
  }
#pragma unroll
  for (int r = 0; r < 2; ++r) {
    float val = fmaxf(acc[r], 0.f);
    vr[h * 2 + r][c] = val;
    v[(r0 + h * 2 + r) * 128 + c] = val;
  }
  __syncthreads();
  float acc2[2];
  const float bv2 = evb[c];
  acc2[0] = bv2; acc2[1] = bv2;
  for (int k4 = 0; k4 < 128; k4 += 4) {
    float w0 = evW[(k4 + 0) * 128 + c], w1 = evW[(k4 + 1) * 128 + c];
    float w2 = evW[(k4 + 2) * 128 + c], w3 = evW[(k4 + 3) * 128 + c];
#pragma unroll
    for (int r = 0; r < 2; ++r) {
      float4 x = *(const float4*)&vr[h * 2 + r][k4];
      acc2[r] += x.x * w0 + x.y * w1 + x.z * w2 + x.w * w3;
    }
  }
#pragma unroll
  for (int r = 0; r < 2; ++r) ev[(r0 + h * 2 + r) * 128 + c] = acc2[r];
}

// ------------- inner edge pass: non-persistent 2048 blocks x 2 cols, lgkm barriers -------------
// e_t[b][j][i][c] transposed layout: block (b,j0) reads/writes one contiguous
// 32KB region. e += relu(e@W + eb + ev_i + ev_j); pve = pre-residual col sums.
// LAST: instead of e write-back, computes edot[b][j][i] = dot(e_new[b,i,j,:], eW3).
template <bool LAST>
__global__ __launch_bounds__(256) void k_edge_inner(bf16_t* __restrict__ e_ws,
    const bf16_t* __restrict__ Wt, const float* __restrict__ eb,
    const float* __restrict__ ev, float* __restrict__ pve,
    const float* __restrict__ eW3, float* __restrict__ edt) {
  __shared__ bf16_t As[2][64][136];   // [jc][i][c], +8 pad
  __shared__ float W3s[128];
  const int b = blockIdx.x >> 5, j0 = (blockIdx.x & 31) * 2;
  const int tid = threadIdx.x;
  const int lane = tid & 63, w = tid >> 6;
  const int quad = lane >> 4, l16 = lane & 15;
  bf16_t* ebase = &e_ws[((size_t)(b * 64 + j0) * 64) * 128];
  // stage 2 e columns: one contiguous 32KB stream
  int4 stg[8];
#pragma unroll
  for (int t = 0; t < 8; ++t) {
    int idx = tid + t * 256;
    stg[t] = *(const int4*)&ebase[idx * 8];
  }
  if (LAST) {
    if (tid < 128) W3s[tid] = eW3[tid];
  }
  // W A-frags in registers (L2-hot): A[m=c][k]
  bf16x8 wf[2][4];
#pragma unroll
  for (int nt = 0; nt < 2; ++nt)
#pragma unroll
    for (int ks = 0; ks < 4; ++ks)
      wf[nt][ks] = *(const bf16x8*)&Wt[(w * 32 + nt * 16 + l16) * 128 + ks * 32 + quad * 8];
  const int c0[2] = {w * 32 + quad * 4, w * 32 + 16 + quad * 4};
  // acc init = eb + ev_j + ev_i (pre-barrier loads)
  f32x4 acc[2][4][2];
  {
    f32x4 ebv[2], evj[2][2], evi[4][2];
#pragma unroll
    for (int nt = 0; nt < 2; ++nt) {
      ebv[nt] = *(const f32x4*)&eb[c0[nt]];
#pragma unroll
      for (int jc = 0; jc < 2; ++jc)
        evj[jc][nt] = *(const f32x4*)&ev[(b * 64 + j0 + jc) * 128 + c0[nt]];
#pragma unroll
      for (int mt = 0; mt < 4; ++mt)
        evi[mt][nt] = *(const f32x4*)&ev[(b * 64 + mt * 16 + l16) * 128 + c0[nt]];
    }
#pragma unroll
    for (int jc = 0; jc < 2; ++jc)
#pragma unroll
      for (int mt = 0; mt < 4; ++mt)
#pragma unroll
        for (int nt = 0; nt < 2; ++nt)
          acc[jc][mt][nt] = ebv[nt] + evj[jc][nt] + evi[mt][nt];
  }
#pragma unroll
  for (int t = 0; t < 8; ++t) {
    int idx = tid + t * 256;
    *(int4*)&As[idx >> 10][(idx >> 4) & 63][(idx & 15) * 8] = stg[t];
  }
  bar_lgkm();
  // MFMA: D[c][i] = sum_k Wt[c][k] * e[i][k]  (64 MFMA per block)
#pragma unroll
  for (int ks = 0; ks < 4; ++ks) {
    bf16x8 ef[2][4];
#pragma unroll
    for (int jc = 0; jc < 2; ++jc)
#pragma unroll
      for (int mt = 0; mt < 4; ++mt)
        ef[jc][mt] = *(const bf16x8*)&As[jc][mt * 16 + l16][ks * 32 + quad * 8];
#pragma unroll
    for (int jc = 0; jc < 2; ++jc)
#pragma unroll
      for (int mt = 0; mt < 4; ++mt)
#pragma unroll
        for (int nt = 0; nt < 2; ++nt)
          acc[jc][mt][nt] = __builtin_amdgcn_mfma_f32_16x16x32_bf16(wf[nt][ks], ef[jc][mt], acc[jc][mt][nt], 0, 0, 0);
  }
  bar_lgkm();  // all MFMA frag reads of As done (LDS-only dep)
  // epilogue: relu, pve, residual from LDS, packed b64 writes to own cells
#pragma unroll
  for (int jc = 0; jc < 2; ++jc) {
#pragma unroll
    for (int nt = 0; nt < 2; ++nt) {
      f32x4 ps = {0.f, 0.f, 0.f, 0.f};
#pragma unroll
      for (int mt = 0; mt < 4; ++mt) {
        const int i = mt * 16 + l16;
        bf16x4 eo = *(const bf16x4*)&As[jc][i][c0[nt]];
        bf16x4 outv;
#pragma unroll
        for (int r = 0; r < 4; ++r) {
          float vv = fmaxf(acc[jc][mt][nt][r], 0.f);
          ps[r] += vv;                            // pve is pre-residual
          outv[r] = (bf16_t)(vv + (float)eo[r]);  // residual
        }
        *(bf16x4*)&As[jc][i][c0[nt]] = outv;
      }
#pragma unroll
      for (int m = 1; m <= 8; m <<= 1) {  // reduce over i (l16 lanes)
#pragma unroll
        for (int r = 0; r < 4; ++r) ps[r] += __shfl_xor(ps[r], m);
      }
      if (l16 == 0) *(f32x4*)&pve[(b * 64 + j0 + jc) * 128 + c0[nt]] = ps;
    }
  }
  bar_lgkm();  // As fully updated (LDS-only dep)
  if (!LAST) {
    // contiguous 32KB write-back
#pragma unroll
    for (int t = 0; t < 8; ++t) {
      int idx = tid + t * 256;
      *(int4*)&ebase[idx * 8] =
          *(const int4*)&As[idx >> 10][(idx >> 4) & 63][(idx & 15) * 8];
    }
  } else {
    // edot[b][j][i] = dot(e_new[b,i,j,:], W3)
    const int i = tid >> 2, q = tid & 3;
#pragma unroll
    for (int jc = 0; jc < 2; ++jc) {
      float d = 0.f;
#pragma unroll
      for (int t = 0; t < 4; ++t) {
        bf16x8 x = *(const bf16x8*)&As[jc][i][q * 32 + t * 8];
#pragma unroll
        for (int u = 0; u < 8; ++u) d += (float)x[u] * W3s[q * 32 + t * 8 + u];
      }
      d += __shfl_xor(d, 1);
      d += __shfl_xor(d, 2);
      if (q == 0) edt[(b * 64 + j0 + jc) * 64 + i] = d;
    }
  }
}

// ------------- inner v pass: v = relu(concat(pve,v)@[256,128]+vb) + v; BN stats. 4 rows/blk ---
__global__ __launch_bounds__(256) void k_v_inner(const float* __restrict__ pve,
    float* __restrict__ v, const float* __restrict__ vW,
    const float* __restrict__ vb, float* __restrict__ stats) {
  __shared__ float in_s[4][256];
  __shared__ float outs[4][132];  // +4 pad
  __shared__ float part[8][2];
  const int r0 = blockIdx.x * 4;
  const int tid = threadIdx.x;
  const int c = tid & 127, h = tid >> 7;
#pragma unroll
  for (int u = 0; u < 2; ++u) {
    int idx = u * 256 + tid;
    int rr = idx >> 7, k = idx & 127;
    in_s[rr][k] = pve[(r0 + rr) * 128 + k];
    in_s[rr][128 + k] = v[(r0 + rr) * 128 + k];
  }
  __syncthreads();
  float acc[2];
  const float bv = vb[c];
  acc[0] = bv; acc[1] = bv;
  for (int k4 = 0; k4 < 256; k4 += 4) {
    float w0 = vW[(k4 + 0) * 128 + c], w1 = vW[(k4 + 1) * 128 + c];
    float w2 = vW[(k4 + 2) * 128 + c], w3 = vW[(k4 + 3) * 128 + c];
#pragma unroll
    for (int r = 0; r < 2; ++r) {
      float4 x = *(const float4*)&in_s[h * 2 + r][k4];
      acc[r] += x.x * w0 + x.y * w1 + x.z * w2 + x.w * w3;
    }
  }
#pragma unroll
  for (int r = 0; r < 2; ++r) {
    float val = fmaxf(acc[r], 0.f) + in_s[h * 2 + r][128 + c];  // relu + residual
    outs[h * 2 + r][c] = val;
    v[(r0 + h * 2 + r) * 128 + c] = val;
  }
  __syncthreads();
  if (tid < 8) {  // parallel BN-stat partial reduction
    int rr = tid >> 1, half = tid & 1;
    float s = 0.f, s2 = 0.f;
    for (int k = 0; k < 64; ++k) {
      float x = outs[rr][half * 64 + k];
      s += x; s2 += x * x;
    }
    part[tid][0] = s;
    part[tid][1] = s2;
  }
  __syncthreads();
  if (tid < 4) {
    int n = (r0 + tid) & 63;
    atomicAdd(&stats[n], part[tid * 2][0] + part[tid * 2 + 1][0]);
    atomicAdd(&stats[64 + n], part[tid * 2][1] + part[tid * 2 + 1][1]);
  }
}

// ------------- g3 final: per-b block, 1024 threads. BN(v), ev3, out_e = edot+eb3+ev3_i+ev3_j,
// pve3 in LDS, out_v. One kernel, 64 blocks. -------------
__global__ __launch_bounds__(1024) void k_g3(const float* __restrict__ vv,
    const float* __restrict__ stats3, const float* __restrict__ g,
    const float* __restrict__ bt, const float* __restrict__ evW3,
    const float* __restrict__ evb3, const float* __restrict__ eb3,
    const float* __restrict__ edt, const float* __restrict__ vW3,
    const float* __restrict__ vb3, float* __restrict__ out_v,
    float* __restrict__ out_e) {
  __shared__ float vbn[64][132];   // +4 pad
  __shared__ float edts[64][68];   // edt[b][j][i], +4 pad
  __shared__ float scs[64], shs[64];
  __shared__ float W3e[128];
  __shared__ float vWs[132];
  __shared__ float ev3s[64];
  __shared__ float pj[16][64];
  const int b = blockIdx.x, tid = threadIdx.x;
  if (tid < 64) {
    float mu = stats3[tid] * (1.f / 8192.f);
    float var = stats3[64 + tid] * (1.f / 8192.f) - mu * mu;
    float sc = rsqrtf(var + 128.f) * g[tid];
    scs[tid] = sc;
    shs[tid] = bt[tid] - mu * sc;
  }
  if (tid < 128) W3e[tid] = evW3[tid];
  if (tid < 129) vWs[tid] = vW3[tid];
  __syncthreads();
#pragma unroll
  for (int t = 0; t < 2; ++t) {  // stage BN(v[b])
    int idx = t * 4096 + tid * 4;
    int row = idx >> 7, cc = idx & 127;
    f32x4 x = *(const f32x4*)&vv[(b * 64 + row) * 128 + cc];
    *(f32x4*)&vbn[row][cc] = x * scs[row] + shs[row];
  }
  {  // stage edot[b]
    int idx = tid * 4;
    int j = idx >> 6, i = idx & 63;
    *(f32x4*)&edts[j][i] = *(const f32x4*)&edt[(b * 64 + j) * 64 + i];
  }
  __syncthreads();
  {  // ev3s[i] = dot(vbn[i], W3e) + evb3; 16 lanes per dot
    int i = tid >> 4, q = tid & 15;
    float d = 0.f;
#pragma unroll
    for (int u = 0; u < 8; ++u) d += vbn[i][q * 8 + u] * W3e[q * 8 + u];
    d += __shfl_xor(d, 1);
    d += __shfl_xor(d, 2);
    d += __shfl_xor(d, 4);
    d += __shfl_xor(d, 8);
    if (q == 0) ev3s[i] = d + evb3[0];
  }
  __syncthreads();
  {  // out_e + per-j partial sums
    int q = tid >> 6, j = tid & 63;  // q 0..15
    float s = 0.f;
    const float e3 = eb3[0];
    const float evj = ev3s[j];
#pragma unroll
    for (int r = 0; r < 4; ++r) {
      int i = q * 4 + r;
      float val = edts[j][i] + e3 + ev3s[i] + evj;
      out_e[(b * 64 + i) * 64 + j] = val;
      s += val;
    }
    pj[q][j] = s;
  }
  __syncthreads();
  {  // out_v[b,n] = pve3*vW[0] + dot(vbn[n], vW[1:129]) + vb
    int n = tid >> 4, q = tid & 15;
    float d = 0.f;
#pragma unroll
    for (int u = 0; u < 8; ++u) d += vbn[n][q * 8 + u] * vWs[1 + q * 8 + u];
    d += __shfl_xor(d, 1);
    d += __shfl_xor(d, 2);
    d += __shfl_xor(d, 4);
    d += __shfl_xor(d, 8);
    if (q == 0) {
      float p3 = 0.f;
#pragma unroll
      for (int qq = 0; qq < 16; ++qq) p3 += pj[qq][n];
      out_v[b * 64 + n] = d + p3 * vWs[0] + vb3[0];
    }
  }
}

extern "C" void kernel_launch(void* const* d_in, const int* in_sizes, int n_in,
                              void* d_out, int out_size, void* d_ws, size_t ws_size,
                              hipStream_t stream) {
  const float* in_v    = (const float*)d_in[0];
  const float* in_e    = (const float*)d_in[1];
  const float* bn_in_g = (const float*)d_in[2];
  const float* bn_in_b = (const float*)d_in[3];
  const float* g1_evW  = (const float*)d_in[4];
  const float* g1_evb  = (const float*)d_in[5];
  const float* g1_eW   = (const float*)d_in[6];
  const float* g1_eb   = (const float*)d_in[7];
  const float* g1_vW   = (const float*)d_in[8];
  const float* g1_vb   = (const float*)d_in[9];
  const float* inn_evW = (const float*)d_in[10];
  const float* inn_evb = (const float*)d_in[11];
  const float* inn_eW  = (const float*)d_in[12];
  const float* inn_eb  = (const float*)d_in[13];
  const float* inn_vW  = (const float*)d_in[14];
  const float* inn_vb  = (const float*)d_in[15];
  const float* bn_g    = (const float*)d_in[16];
  const float* bn_b    = (const float*)d_in[17];
  const float* g3_evW  = (const float*)d_in[18];
  const float* g3_evb  = (const float*)d_in[19];
  const float* g3_eW   = (const float*)d_in[20];
  const float* g3_eb   = (const float*)d_in[21];
  const float* g3_vW   = (const float*)d_in[22];
  const float* g3_vb   = (const float*)d_in[23];

  char* ws = (char*)d_ws;
  bf16_t* e_ws = (bf16_t*)(ws);                       // 64MB : e_t[b][j][i][c] bf16
  float* v     = (float*)(ws + 67108864);             // 2MB
  float* ev    = (float*)(ws + 69206016);             // 2MB
  float* pve   = (float*)(ws + 71303168);             // 2MB
  float* v0    = (float*)(ws + 73400320);             // 512KB
  bf16_t* Wt   = (bf16_t*)(ws + 73924608);            // 128KB
  float* edt   = (float*)(ws + 74055680);             // 1MB : edot[b][j][i]
  float* stats = (float*)(ws + 75104256);             // 2KB (4 layers x 128 f32)

  float* out_v = (float*)d_out;          // [B,N,1] = 4096
  float* out_e = (float*)d_out + 4096;   // [B,N,N,1] = 262144

  k_prep<<<265, 256, 0, stream>>>(in_v, bn_in_g, bn_in_b, inn_eW, v0, Wt, stats);

  // ---- g1 ----
  k_ev<32><<<1024, 256, 0, stream>>>(v0, g1_evW, g1_evb, ev);
  k_edge_g1<<<2048, 256, 0, stream>>>(in_e, g1_eW, g1_eb, ev, e_ws, pve);
  k_vg1_ev<<<1024, 256, 0, stream>>>(pve, v0, g1_vW, g1_vb, inn_evW, inn_evb, v, ev);

  // ---- inner layers ----
  for (int l = 0; l < 4; ++l) {
    if (l > 0)
      k_evbn<<<1024, 256, 0, stream>>>(v, stats + (l - 1) * 128, bn_g + (l - 1) * 64,
                                       bn_b + (l - 1) * 64, inn_evW + l * 16384,
                                       inn_evb + l * 128, ev);
    if (l < 3)
      k_edge_inner<false><<<2048, 256, 0, stream>>>(e_ws, Wt + l * 16384,
          inn_eb + l * 128, ev, pve, g3_eW, edt);
    else
      k_edge_inner<true><<<2048, 256, 0, stream>>>(e_ws, Wt + l * 16384,
          inn_eb + l * 128, ev, pve, g3_eW, edt);
    k_v_inner<<<1024, 256, 0, stream>>>(pve, v, inn_vW + l * 32768, inn_vb + l * 128,
                                        stats + l * 128);
  }

  // ---- g3 final (BN of layer 3 on the fly; pve3 in-block) ----
  k_g3<<<64, 1024, 0, stream>>>(v, stats + 384, bn_g + 192, bn_b + 192,
                                g3_evW, g3_evb, g3_eb, edt, g3_vW, g3_vb,
                                out_v, out_e);
}